// Round 16
// baseline (2085.961 us; speedup 1.0000x reference)
//
#include <hip/hip_runtime.h>
#include <cstdint>
#include <cstddef>

// ---------- types ----------
typedef __attribute__((ext_vector_type(8))) short short8;   // 8 bf16 in 4 VGPRs
typedef __attribute__((ext_vector_type(4))) float f32x4;

#define B_ 64
#define T_ 512
#define I_ 256
#define H_ 1024
#define O_ 256

__device__ __forceinline__ unsigned short f32_to_bf16(float f) {
  unsigned int u = __float_as_uint(f);
  u += 0x7fffu + ((u >> 16) & 1u);           // RNE
  return (unsigned short)(u >> 16);
}
__device__ __forceinline__ float bf16_to_f32(unsigned short h) {
  return __uint_as_float(((unsigned int)h) << 16);
}

__device__ __forceinline__ void gload_lds16(const void* g, void* l) {
  __builtin_amdgcn_global_load_lds((const __attribute__((address_space(1))) void*)g,
                                   (__attribute__((address_space(3))) void*)l, 16, 0, 0);
}

// MALL-write-through stores (bypass L1/L2 -> no cache maintenance ever needed)
__device__ __forceinline__ void store_short_sc(void* p, unsigned short v) {
  unsigned int vv = v;
  asm volatile("global_store_short %0, %1, off sc0 sc1" :: "v"(p), "v"(vv) : "memory");
}
__device__ __forceinline__ void store_int_sc(void* p, int v) {
  asm volatile("global_store_dword %0, %1, off sc0 sc1" :: "v"(p), "v"(v) : "memory");
}
// MALL-coherent 16B load (inline asm: caller MUST s_waitcnt vmcnt before use!)
__device__ __forceinline__ short8 load16_sc(const void* p) {
  short8 r;
  asm volatile("global_load_dwordx4 %0, %1, off sc0 sc1" : "=v"(r) : "v"(p) : "memory");
  return r;
}
// pinned (non-rematerializable) 16B load: executes exactly once (cached path ok)
__device__ __forceinline__ short8 pinned_load16(const void* p) {
  short8 r;
  asm volatile("global_load_dwordx4 %0, %1, off" : "=v"(r) : "v"(p));
  return r;
}

// ---------- conversion kernels ----------
__global__ void cvt_f32_bf16(const float4* __restrict__ s, ushort4* __restrict__ d, int n4) {
  int i = blockIdx.x * blockDim.x + threadIdx.x;
  if (i >= n4) return;
  float4 v = s[i];
  ushort4 o;
  o.x = f32_to_bf16(v.x); o.y = f32_to_bf16(v.y);
  o.z = f32_to_bf16(v.z); o.w = f32_to_bf16(v.w);
  d[i] = o;
}

__global__ void bias_sum(const float* __restrict__ a, const float* __restrict__ b,
                         float* __restrict__ o, int n) {
  int i = blockIdx.x * blockDim.x + threadIdx.x;
  if (i < n) o[i] = a[i] + b[i];
}

// ---------- GEMM: C[M,N] = A[M,K] @ Bm[N,K]^T + bias, 128x128 tile (m97 structure) ----------
template<int OUT_F32>
__global__ __launch_bounds__(256) void gemm_bt(
    const unsigned short* __restrict__ A, const unsigned short* __restrict__ Bm,
    const float* __restrict__ bias, void* __restrict__ Cout, int N_, int K_)
{
  __shared__ unsigned short As[128*32];
  __shared__ unsigned short Bs[128*32];
  const int tid = threadIdx.x;
  const int l = tid & 63, w = tid >> 6;
  const int row0 = blockIdx.y * 128, col0 = blockIdx.x * 128;
  const int wr = w >> 1, wc = w & 1;          // 2x2 waves, each 64x64
  const int lrow = l & 15, lk8 = (l >> 4) * 8;

  f32x4 acc[4][4] = {};

  const int nkb = K_ >> 5;
  for (int kb = 0; kb < nkb; ++kb) {
    #pragma unroll
    for (int c = 0; c < 2; ++c) {
      const int off = w*2048 + c*1024 + l*16;   // byte offset within 8KB tile
      const int row = off >> 6, colb = off & 63;
      gload_lds16((const char*)A  + ((size_t)(row0+row)*K_ + kb*32)*2 + colb,
                  (char*)As + w*2048 + c*1024);
      gload_lds16((const char*)Bm + ((size_t)(col0+row)*K_ + kb*32)*2 + colb,
                  (char*)Bs + w*2048 + c*1024);
    }
    __syncthreads();
    short8 af[4], bfr[4];
    #pragma unroll
    for (int m=0;m<4;++m) af[m]  = *(const short8*)&As[(wr*64 + m*16 + lrow)*32 + lk8];
    #pragma unroll
    for (int n=0;n<4;++n) bfr[n] = *(const short8*)&Bs[(wc*64 + n*16 + lrow)*32 + lk8];
    #pragma unroll
    for (int m=0;m<4;++m)
      #pragma unroll
      for (int n=0;n<4;++n)
        acc[m][n] = __builtin_amdgcn_mfma_f32_16x16x32_bf16(af[m], bfr[n], acc[m][n], 0,0,0);
    __syncthreads();
  }

  #pragma unroll
  for (int n=0;n<4;++n) {
    const int col = col0 + wc*64 + n*16 + lrow;
    const float bv = bias[col];
    #pragma unroll
    for (int m=0;m<4;++m) {
      const int rowb = row0 + wr*64 + m*16 + (l>>4)*4;
      #pragma unroll
      for (int r=0;r<4;++r) {
        const float v = acc[m][n][r] + bv;
        if (OUT_F32) ((float*)Cout)[(size_t)(rowb+r)*N_ + col] = v;
        else ((unsigned short*)Cout)[(size_t)(rowb+r)*N_ + col] = f32_to_bf16(v);
      }
    }
  }
}

// ---------- fused decoupled 2-layer RNN ----------
// 256 wgs x 512 threads, LB(512,2) — 1 wg/CU on all 256 CUs.
// ENVELOPE LAW (r6/7/8/10/14 post-mortems): 512-thr wg => 2 waves/SIMD =>
// <=256 regs/wave TOTAL; never asm-pin more than 128 regs/wave.
// wgs 0-127: LAYER 0 = r5's proven scan (fan-in 8, ~2.4us/step), publish-all-t.
// wgs 128-255: LAYER 1 wave-role split (waves 0-3 pin Wih1 -> aI; waves 4-7
//   pin Whh1 -> aH; LDS comb handoff). Fan-in 16 (structurally forced).
// r16 delta (L1 staging only): PUBLISH-FIRST — flags1 published immediately
// after the h2-store drain+sync, BEFORE poll0 and the h1 issue. Removes
// poll0-RT + h1-read-RT from the publish latency every peer wg waits on.
#define L0_STEP(tcur, XREG)                                                          \
  {                                                                                  \
    const int t = (tcur);                                                            \
    f32x4 acc0 = {}, acc1 = {}, acc2 = {}, acc3 = {};                                \
    if (t > 0) {                                                                     \
      _Pragma("unroll")                                                              \
      for (int kk = 0; kk < 32; kk += 4) {                                           \
        short8 a0 = *(const short8*)&lds_h1[arow][(kk+0)*32 + lk8];                  \
        short8 a1 = *(const short8*)&lds_h1[arow][(kk+1)*32 + lk8];                  \
        short8 a2 = *(const short8*)&lds_h1[arow][(kk+2)*32 + lk8];                  \
        short8 a3 = *(const short8*)&lds_h1[arow][(kk+3)*32 + lk8];                  \
        acc0 = __builtin_amdgcn_mfma_f32_16x16x32_bf16(a0, breg[kk+0], acc0, 0,0,0); \
        acc1 = __builtin_amdgcn_mfma_f32_16x16x32_bf16(a1, breg[kk+1], acc1, 0,0,0); \
        acc2 = __builtin_amdgcn_mfma_f32_16x16x32_bf16(a2, breg[kk+2], acc2, 0,0,0); \
        acc3 = __builtin_amdgcn_mfma_f32_16x16x32_bf16(a3, breg[kk+3], acc3, 0,0,0); \
      }                                                                              \
    }                                                                                \
    if (l < 16) {                                                                    \
      _Pragma("unroll")                                                              \
      for (int r = 0; r < 4; ++r) {                                                  \
        const int s = sg*4 + r;                                                      \
        float v = acc0[r] + acc1[r] + acc2[r] + acc3[r]                              \
                + bf16_to_f32((unsigned short)XREG[r]);                              \
        v = fmaxf(v, 0.f);                                                           \
        store_short_sc(h1buf + ((size_t)s*T_ + t)*H_ + col, f32_to_bf16(v));         \
      }                                                                              \
    }                                                                                \
    asm volatile("s_waitcnt vmcnt(0)" ::: "memory");     /* h1 stores at MALL */     \
    __syncthreads();                                     /* all 8 waves drained */   \
    if (tid == 0) store_int_sc(&flags0g[rgO], t+1);      /* publish ALL t */         \
    if (t < T_-1) {                                                                  \
      { int fv;                                                                      \
        do { fv = __hip_atomic_load(flags0g + (l & 7), __ATOMIC_RELAXED,             \
                                    __HIP_MEMORY_SCOPE_AGENT);                       \
        } while (!__all(fv >= t+1)); }                                               \
      const unsigned short* hrow = h1buf + ((size_t)(sg*4 + (w>>1))*T_ + t)*H_;      \
      const int tn = (t+2 < T_) ? (t+2) : (T_-1);                                    \
      const unsigned short* xpp = xp + ((size_t)(sg*4)*T_ + tn)*H_ + col;            \
      short8 sv = load16_sc(hrow + (w&1)*512 + l*8);     /* 1 outstanding */         \
      _Pragma("unroll")                                                              \
      for (int r = 0; r < 4; ++r)                        /* +4 outstanding */        \
        asm volatile("global_load_ushort %0, %1, off"                               \
                     : "=v"(XREG[r]) : "v"(xpp + (size_t)r*T_*H_) : "memory");       \
      asm volatile("s_waitcnt vmcnt(4)" ::: "memory");   /* wait stage load only */  \
      *(short8*)&lds_h1[w>>1][(w&1)*512 + l*8] = sv;                                 \
      __syncthreads();                                   /* LDS visible for t+1 */   \
    }                                                                                \
  }

__global__ __launch_bounds__(512, 2) void rnn_fused(
    const unsigned short* __restrict__ whh0,
    const unsigned short* __restrict__ wih1,
    const unsigned short* __restrict__ whh1,
    const unsigned short* __restrict__ xp,     // xp0 = x@Wih0^T + b  [B][T][H]
    const float* __restrict__ bias1,           // bih1 + bhh1
    unsigned short* __restrict__ h1buf,        // H1 [B][T][H] (full, no overwrite)
    unsigned short* __restrict__ h2pp,         // [2][B][H]; final h2 in slot 1
    int* __restrict__ bar)
{
  // 35,328 B static LDS (stay < 64KB — r10 lesson)
  __shared__ unsigned short lds_h1[8][1040];   // L0 uses rows 0..3 only
  __shared__ unsigned short lds_h2[8][1040];
  __shared__ float comb[4][8][16];             // L1 aH handoff

  const int wg = blockIdx.x;            // 0..255
  const int tid = threadIdx.x;          // 0..511
  const int l = tid & 63;
  const int w = tid >> 6;               // 0..7
  const int lrow = l & 15;
  const int lk8 = (l >> 4) * 8;

  if (wg < 128) {
    // ================= LAYER 0 (r5 verbatim, publish-all-t) =================
    const int sg = wg & 15;             // 4 samples
    const int rgO = wg >> 4;            // 0..7 (128 cols)
    const int col = rgO*128 + w*16 + lrow;
    const int arow = lrow & 3;
    int* flags0g = bar + sg*16;

    short8 breg[32];
    #pragma unroll
    for (int kk=0; kk<32; ++kk)
      breg[kk] = pinned_load16(&whh0[(size_t)col*H_ + kk*32 + lk8]);

    unsigned int xa[4], xb[4];
    #pragma unroll
    for (int r=0; r<4; ++r) {
      asm volatile("global_load_ushort %0, %1, off" : "=v"(xa[r])
        : "v"(xp + ((size_t)(sg*4+r)*T_ + 0)*H_ + col) : "memory");
      asm volatile("global_load_ushort %0, %1, off" : "=v"(xb[r])
        : "v"(xp + ((size_t)(sg*4+r)*T_ + 1)*H_ + col) : "memory");
    }
    asm volatile("s_waitcnt vmcnt(0)" ::: "memory");
    __builtin_amdgcn_sched_barrier(0);

    for (int t2 = 0; t2 < T_; t2 += 2) {
      L0_STEP(t2,   xa);
      L0_STEP(t2+1, xb);
    }
  } else {
    // ================= LAYER 1 (wave-role split, self-paced) =================
    const int lw = wg - 128;
    const int sg1 = lw >> 4;            // 0..7 (8 samples)
    const int rgO1 = lw & 15;           // 0..15 (64 cols)
    const int q = w & 3;                // col quad within wg
    const bool isI = (w < 4);           // waves 0-3: Wih1; 4-7: Whh1
    const int col = rgO1*64 + q*16 + lrow;
    const int arow = lrow & 7;          // 8 samples dup to 16 rows
    int* flags1g = bar + 1024 + sg1*16;
    const int fi0 = (2*sg1 + ((l>>3)&1))*16 + (l&7);   // L0 flags for my samples

    const unsigned short* wsel = isI ? wih1 : whh1;
    short8 breg[32];
    #pragma unroll
    for (int kk=0; kk<32; ++kk)
      breg[kk] = pinned_load16(&wsel[(size_t)col*H_ + kk*32 + lk8]);
    asm volatile("s_waitcnt vmcnt(0)" ::: "memory");
    __builtin_amdgcn_sched_barrier(0);

    const float b1v = bias1[col];

    // prologue: wait h1_0, stage into lds_h1 (wave w -> sample row w)
    { int fv;
      do { fv = __hip_atomic_load(bar + fi0, __ATOMIC_RELAXED,
                                  __HIP_MEMORY_SCOPE_AGENT);
      } while (!__all(fv >= 1)); }
    {
      short8 s0 = load16_sc(h1buf + ((size_t)(sg1*8 + w)*T_ + 0)*H_ + l*8);
      short8 s1 = load16_sc(h1buf + ((size_t)(sg1*8 + w)*T_ + 0)*H_ + 512 + l*8);
      asm volatile("s_waitcnt vmcnt(0)" ::: "memory");
      *(short8*)&lds_h1[w][l*8]       = s0;
      *(short8*)&lds_h1[w][512 + l*8] = s1;
      __syncthreads();
    }

    for (int s = 0; s < T_; ++s) {
      f32x4 a0 = {}, a1 = {};
      if (isI) {
        #pragma unroll
        for (int kk = 0; kk < 32; kk += 2) {
          short8 x0 = *(const short8*)&lds_h1[arow][(kk+0)*32 + lk8];
          short8 x1 = *(const short8*)&lds_h1[arow][(kk+1)*32 + lk8];
          a0 = __builtin_amdgcn_mfma_f32_16x16x32_bf16(x0, breg[kk+0], a0, 0,0,0);
          a1 = __builtin_amdgcn_mfma_f32_16x16x32_bf16(x1, breg[kk+1], a1, 0,0,0);
        }
      } else {
        if (s > 0) {
          #pragma unroll
          for (int kk = 0; kk < 32; kk += 2) {
            short8 x0 = *(const short8*)&lds_h2[arow][(kk+0)*32 + lk8];
            short8 x1 = *(const short8*)&lds_h2[arow][(kk+1)*32 + lk8];
            a0 = __builtin_amdgcn_mfma_f32_16x16x32_bf16(x0, breg[kk+0], a0, 0,0,0);
            a1 = __builtin_amdgcn_mfma_f32_16x16x32_bf16(x1, breg[kk+1], a1, 0,0,0);
          }
        }
        if (l < 32) {
          #pragma unroll
          for (int r = 0; r < 4; ++r)
            comb[q][(l>>4)*4 + r][lrow] = a0[r] + a1[r];
        }
      }
      __syncthreads();                                   // comb visible
      if (isI && l < 32) {
        #pragma unroll
        for (int r = 0; r < 4; ++r) {
          const int smp = sg1*8 + (l>>4)*4 + r;
          float v = a0[r] + a1[r] + comb[q][(l>>4)*4 + r][lrow] + b1v;
          v = fmaxf(v, 0.f);
          store_short_sc(h2pp + ((size_t)((s&1)*B_ + smp))*H_ + col, f32_to_bf16(v));
        }
      }
      if (s < T_-1) {
        // ---- r16: PUBLISH-FIRST staging ----
        // (1) drain h2 stores; wg-sync; publish immediately
        asm volatile("s_waitcnt vmcnt(0)" ::: "memory");  // h2 stores at MALL
        __syncthreads();                                  // all storing waves drained
        if (tid == 0) store_int_sc(&flags1g[rgO1], s+1);
        // (2) flags0 poll (single load) — L0 leads; ~1 RT
        { int v0;
          do { v0 = __hip_atomic_load(bar + fi0, __ATOMIC_RELAXED,
                                      __HIP_MEMORY_SCOPE_AGENT);
          } while (!__all(v0 >= s+2)); }
        // (3) issue h1_{s+1} loads — RT rides under the flags1 poll
        short8 t0 = load16_sc(h1buf + ((size_t)(sg1*8 + w)*T_ + (s+1))*H_ + l*8);
        short8 t1 = load16_sc(h1buf + ((size_t)(sg1*8 + w)*T_ + (s+1))*H_ + 512 + l*8);
        // (4) flags1 poll (single load) — publishes arrived ~2 RTs earlier now
        { int v1;
          do { v1 = __hip_atomic_load(flags1g + (l & 15), __ATOMIC_RELAXED,
                                      __HIP_MEMORY_SCOPE_AGENT);
          } while (!__all(v1 >= s+1)); }
        // (5) h2 loads + drain + LDS + sync
        short8 t2 = load16_sc(h2pp + ((size_t)((s&1)*B_ + sg1*8 + w))*H_ + l*8);
        short8 t3 = load16_sc(h2pp + ((size_t)((s&1)*B_ + sg1*8 + w))*H_ + 512 + l*8);
        asm volatile("s_waitcnt vmcnt(0)" ::: "memory");
        *(short8*)&lds_h1[w][l*8]       = t0;
        *(short8*)&lds_h1[w][512 + l*8] = t1;
        *(short8*)&lds_h2[w][l*8]       = t2;
        *(short8*)&lds_h2[w][512 + l*8] = t3;
        __syncthreads();
      } else {
        // final step: drain h2_511 stores before kernel end (fc reads next)
        asm volatile("s_waitcnt vmcnt(0)" ::: "memory");
      }
    }
  }
}

// ---------- final FC: out[64,256] = h2 @ fcW^T + fcb (f32 out) ----------
__global__ __launch_bounds__(64) void fc_kernel(const unsigned short* __restrict__ h,
                                                const unsigned short* __restrict__ fw,
                                                const float* __restrict__ fb,
                                                float* __restrict__ out) {
  const int l = threadIdx.x;
  const int bx = blockIdx.x, by = blockIdx.y;   // bx: 16 col tiles, by: 4 row tiles
  const int lrow = l & 15, lk8 = (l>>4)*8;
  f32x4 acc = {};
  #pragma unroll
  for (int kk=0; kk<32; ++kk) {
    short8 a = *(const short8*)&h [(size_t)(by*16 + lrow)*H_ + kk*32 + lk8];
    short8 b = *(const short8*)&fw[(size_t)(bx*16 + lrow)*H_ + kk*32 + lk8];
    acc = __builtin_amdgcn_mfma_f32_16x16x32_bf16(a, b, acc, 0,0,0);
  }
  const int col = bx*16 + lrow;
  const float bv = fb[col];
  #pragma unroll
  for (int r=0;r<4;++r) {
    const int row = by*16 + (l>>4)*4 + r;
    out[row*O_ + col] = acc[r] + bv;
  }
}

// ---------- launch ----------
extern "C" void kernel_launch(void* const* d_in, const int* in_sizes, int n_in,
                              void* d_out, int out_size, void* d_ws, size_t ws_size,
                              hipStream_t stream) {
  const float* x    = (const float*)d_in[0];
  const float* wih0 = (const float*)d_in[1];
  const float* bih0 = (const float*)d_in[2];
  const float* whh0 = (const float*)d_in[3];
  const float* bhh0 = (const float*)d_in[4];
  const float* wih1 = (const float*)d_in[5];
  const float* bih1 = (const float*)d_in[6];
  const float* whh1 = (const float*)d_in[7];
  const float* bhh1 = (const float*)d_in[8];
  const float* fcw  = (const float*)d_in[9];
  const float* fcb  = (const float*)d_in[10];

  char* ws = (char*)d_ws;
  // workspace layout (bytes)
  unsigned short* XBF  = (unsigned short*)(ws + 0);          // 16,777,216  x bf16
  unsigned short* WIH0 = (unsigned short*)(ws + 16777216);   //    524,288
  unsigned short* WHH0 = (unsigned short*)(ws + 17301504);   //  2,097,152
  unsigned short* WIH1 = (unsigned short*)(ws + 19398656);   //  2,097,152
  unsigned short* WHH1 = (unsigned short*)(ws + 21495808);   //  2,097,152
  unsigned short* FCW  = (unsigned short*)(ws + 23592960);   //    524,288
  float*          BIAS0= (float*)(ws + 24117248);            //      4,096
  float*          BIAS1= (float*)(ws + 24121344);            //      4,096
  unsigned short* XP   = (unsigned short*)(ws + 24125440);   // 67,108,864  xp0 [B][T][H]
  unsigned short* H1   = (unsigned short*)(ws + 91234304);   // 67,108,864  h1 [B][T][H]
  unsigned short* H2PP = (unsigned short*)(ws + 158343168);  //    262,144  h2 ping-pong
  int*            BAR  = (int*)(ws + 158605312);             //      8,192  flag lines

  // flags0 at BAR[0..255], flags1 at BAR[1024..1151] — all re-zeroed in-graph
  hipMemsetAsync(BAR, 0, 8192, stream);

  // fp32 -> bf16 conversions
  cvt_f32_bf16<<<dim3(8192), 256, 0, stream>>>((const float4*)x,    (ushort4*)XBF,  2097152);
  cvt_f32_bf16<<<dim3(256),  256, 0, stream>>>((const float4*)wih0, (ushort4*)WIH0, 65536);
  cvt_f32_bf16<<<dim3(1024), 256, 0, stream>>>((const float4*)whh0, (ushort4*)WHH0, 262144);
  cvt_f32_bf16<<<dim3(1024), 256, 0, stream>>>((const float4*)wih1, (ushort4*)WIH1, 262144);
  cvt_f32_bf16<<<dim3(1024), 256, 0, stream>>>((const float4*)whh1, (ushort4*)WHH1, 262144);
  cvt_f32_bf16<<<dim3(256),  256, 0, stream>>>((const float4*)fcw,  (ushort4*)FCW,  65536);
  bias_sum<<<dim3(4), 256, 0, stream>>>(bih0, bhh0, BIAS0, H_);
  bias_sum<<<dim3(4), 256, 0, stream>>>(bih1, bhh1, BIAS1, H_);

  // xp0 = x @ Wih0^T + (bih0+bhh0)   [M=32768, N=1024, K=256]
  gemm_bt<0><<<dim3(8, 256), 256, 0, stream>>>(XBF, WIH0, BIAS0, XP, H_, I_);
  // fused decoupled 2-layer scan; final h2 lands in H2PP slot 1
  rnn_fused<<<dim3(256), 512, 0, stream>>>(WHH0, WIH1, WHH1, XP, BIAS1, H1, H2PP, BAR);
  // out = h2_last @ fcW^T + fcb
  fc_kernel<<<dim3(16, 4), 64, 0, stream>>>(H2PP + (size_t)B_*H_, FCW, fcb, (float*)d_out);
}

// Round 17
// 2008.285 us; speedup vs baseline: 1.0387x; 1.0387x over previous
//
#include <hip/hip_runtime.h>
#include <cstdint>
#include <cstddef>

// ---------- types ----------
typedef __attribute__((ext_vector_type(8))) short short8;   // 8 bf16 in 4 VGPRs
typedef __attribute__((ext_vector_type(4))) float f32x4;

#define B_ 64
#define T_ 512
#define I_ 256
#define H_ 1024
#define O_ 256

__device__ __forceinline__ unsigned short f32_to_bf16(float f) {
  unsigned int u = __float_as_uint(f);
  u += 0x7fffu + ((u >> 16) & 1u);           // RNE
  return (unsigned short)(u >> 16);
}
__device__ __forceinline__ float bf16_to_f32(unsigned short h) {
  return __uint_as_float(((unsigned int)h) << 16);
}

__device__ __forceinline__ void gload_lds16(const void* g, void* l) {
  __builtin_amdgcn_global_load_lds((const __attribute__((address_space(1))) void*)g,
                                   (__attribute__((address_space(3))) void*)l, 16, 0, 0);
}

// MALL-write-through stores (bypass L1/L2 -> no cache maintenance ever needed)
__device__ __forceinline__ void store_short_sc(void* p, unsigned short v) {
  unsigned int vv = v;
  asm volatile("global_store_short %0, %1, off sc0 sc1" :: "v"(p), "v"(vv) : "memory");
}
__device__ __forceinline__ void store_int_sc(void* p, int v) {
  asm volatile("global_store_dword %0, %1, off sc0 sc1" :: "v"(p), "v"(v) : "memory");
}
// MALL-coherent 16B load (inline asm: caller MUST s_waitcnt vmcnt before use!)
__device__ __forceinline__ short8 load16_sc(const void* p) {
  short8 r;
  asm volatile("global_load_dwordx4 %0, %1, off sc0 sc1" : "=v"(r) : "v"(p) : "memory");
  return r;
}
// pinned (non-rematerializable) 16B load: executes exactly once (cached path ok)
__device__ __forceinline__ short8 pinned_load16(const void* p) {
  short8 r;
  asm volatile("global_load_dwordx4 %0, %1, off" : "=v"(r) : "v"(p));
  return r;
}

// ---------- conversion kernels ----------
__global__ void cvt_f32_bf16(const float4* __restrict__ s, ushort4* __restrict__ d, int n4) {
  int i = blockIdx.x * blockDim.x + threadIdx.x;
  if (i >= n4) return;
  float4 v = s[i];
  ushort4 o;
  o.x = f32_to_bf16(v.x); o.y = f32_to_bf16(v.y);
  o.z = f32_to_bf16(v.z); o.w = f32_to_bf16(v.w);
  d[i] = o;
}

__global__ void bias_sum(const float* __restrict__ a, const float* __restrict__ b,
                         float* __restrict__ o, int n) {
  int i = blockIdx.x * blockDim.x + threadIdx.x;
  if (i < n) o[i] = a[i] + b[i];
}

// ---------- GEMM: C[M,N] = A[M,K] @ Bm[N,K]^T + bias, 128x128 tile (m97 structure) ----------
template<int OUT_F32>
__global__ __launch_bounds__(256) void gemm_bt(
    const unsigned short* __restrict__ A, const unsigned short* __restrict__ Bm,
    const float* __restrict__ bias, void* __restrict__ Cout, int N_, int K_)
{
  __shared__ unsigned short As[128*32];
  __shared__ unsigned short Bs[128*32];
  const int tid = threadIdx.x;
  const int l = tid & 63, w = tid >> 6;
  const int row0 = blockIdx.y * 128, col0 = blockIdx.x * 128;
  const int wr = w >> 1, wc = w & 1;          // 2x2 waves, each 64x64
  const int lrow = l & 15, lk8 = (l >> 4) * 8;

  f32x4 acc[4][4] = {};

  const int nkb = K_ >> 5;
  for (int kb = 0; kb < nkb; ++kb) {
    #pragma unroll
    for (int c = 0; c < 2; ++c) {
      const int off = w*2048 + c*1024 + l*16;   // byte offset within 8KB tile
      const int row = off >> 6, colb = off & 63;
      gload_lds16((const char*)A  + ((size_t)(row0+row)*K_ + kb*32)*2 + colb,
                  (char*)As + w*2048 + c*1024);
      gload_lds16((const char*)Bm + ((size_t)(col0+row)*K_ + kb*32)*2 + colb,
                  (char*)Bs + w*2048 + c*1024);
    }
    __syncthreads();
    short8 af[4], bfr[4];
    #pragma unroll
    for (int m=0;m<4;++m) af[m]  = *(const short8*)&As[(wr*64 + m*16 + lrow)*32 + lk8];
    #pragma unroll
    for (int n=0;n<4;++n) bfr[n] = *(const short8*)&Bs[(wc*64 + n*16 + lrow)*32 + lk8];
    #pragma unroll
    for (int m=0;m<4;++m)
      #pragma unroll
      for (int n=0;n<4;++n)
        acc[m][n] = __builtin_amdgcn_mfma_f32_16x16x32_bf16(af[m], bfr[n], acc[m][n], 0,0,0);
    __syncthreads();
  }

  #pragma unroll
  for (int n=0;n<4;++n) {
    const int col = col0 + wc*64 + n*16 + lrow;
    const float bv = bias[col];
    #pragma unroll
    for (int m=0;m<4;++m) {
      const int rowb = row0 + wr*64 + m*16 + (l>>4)*4;
      #pragma unroll
      for (int r=0;r<4;++r) {
        const float v = acc[m][n][r] + bv;
        if (OUT_F32) ((float*)Cout)[(size_t)(rowb+r)*N_ + col] = v;
        else ((unsigned short*)Cout)[(size_t)(rowb+r)*N_ + col] = f32_to_bf16(v);
      }
    }
  }
}

// ---------- fused decoupled 2-layer RNN ----------
// 256 wgs x 512 threads, LB(512,2) — 1 wg/CU on all 256 CUs.
// ENVELOPE LAW (r6/7/8/10/14 post-mortems): 512-thr wg => 2 waves/SIMD =>
// <=256 regs/wave TOTAL; never asm-pin more than 128 regs/wave.
// wgs 0-127: LAYER 0 = r5's proven scan (fan-in 8, ~2.4us/step), publish-all-t.
// wgs 128-255: LAYER 1 wave-role split (waves 0-3 pin Wih1 -> aI; waves 4-7
//   pin Whh1 -> aH; LDS comb handoff). Fan-in 16 (structurally forced).
// r17 delta (L1 staging only): r15's proven order (poll0 rides the store
// drain) MINUS the explicit h1-read drain before sync — the h1 RT now folds
// under poll1's observe wait (in-order vmcnt: poll1's load-result wait drains
// the h1 loads implicitly). One fewer serial MALL RT per step. r16's
// publish-first was falsified (stores are fire-and-forget) and is reverted.
#define L0_STEP(tcur, XREG)                                                          \
  {                                                                                  \
    const int t = (tcur);                                                            \
    f32x4 acc0 = {}, acc1 = {}, acc2 = {}, acc3 = {};                                \
    if (t > 0) {                                                                     \
      _Pragma("unroll")                                                              \
      for (int kk = 0; kk < 32; kk += 4) {                                           \
        short8 a0 = *(const short8*)&lds_h1[arow][(kk+0)*32 + lk8];                  \
        short8 a1 = *(const short8*)&lds_h1[arow][(kk+1)*32 + lk8];                  \
        short8 a2 = *(const short8*)&lds_h1[arow][(kk+2)*32 + lk8];                  \
        short8 a3 = *(const short8*)&lds_h1[arow][(kk+3)*32 + lk8];                  \
        acc0 = __builtin_amdgcn_mfma_f32_16x16x32_bf16(a0, breg[kk+0], acc0, 0,0,0); \
        acc1 = __builtin_amdgcn_mfma_f32_16x16x32_bf16(a1, breg[kk+1], acc1, 0,0,0); \
        acc2 = __builtin_amdgcn_mfma_f32_16x16x32_bf16(a2, breg[kk+2], acc2, 0,0,0); \
        acc3 = __builtin_amdgcn_mfma_f32_16x16x32_bf16(a3, breg[kk+3], acc3, 0,0,0); \
      }                                                                              \
    }                                                                                \
    if (l < 16) {                                                                    \
      _Pragma("unroll")                                                              \
      for (int r = 0; r < 4; ++r) {                                                  \
        const int s = sg*4 + r;                                                      \
        float v = acc0[r] + acc1[r] + acc2[r] + acc3[r]                              \
                + bf16_to_f32((unsigned short)XREG[r]);                              \
        v = fmaxf(v, 0.f);                                                           \
        store_short_sc(h1buf + ((size_t)s*T_ + t)*H_ + col, f32_to_bf16(v));         \
      }                                                                              \
    }                                                                                \
    asm volatile("s_waitcnt vmcnt(0)" ::: "memory");     /* h1 stores at MALL */     \
    __syncthreads();                                     /* all 8 waves drained */   \
    if (tid == 0) store_int_sc(&flags0g[rgO], t+1);      /* publish ALL t */         \
    if (t < T_-1) {                                                                  \
      { int fv;                                                                      \
        do { fv = __hip_atomic_load(flags0g + (l & 7), __ATOMIC_RELAXED,             \
                                    __HIP_MEMORY_SCOPE_AGENT);                       \
        } while (!__all(fv >= t+1)); }                                               \
      const unsigned short* hrow = h1buf + ((size_t)(sg*4 + (w>>1))*T_ + t)*H_;      \
      const int tn = (t+2 < T_) ? (t+2) : (T_-1);                                    \
      const unsigned short* xpp = xp + ((size_t)(sg*4)*T_ + tn)*H_ + col;            \
      short8 sv = load16_sc(hrow + (w&1)*512 + l*8);     /* 1 outstanding */         \
      _Pragma("unroll")                                                              \
      for (int r = 0; r < 4; ++r)                        /* +4 outstanding */        \
        asm volatile("global_load_ushort %0, %1, off"                               \
                     : "=v"(XREG[r]) : "v"(xpp + (size_t)r*T_*H_) : "memory");       \
      asm volatile("s_waitcnt vmcnt(4)" ::: "memory");   /* wait stage load only */  \
      *(short8*)&lds_h1[w>>1][(w&1)*512 + l*8] = sv;                                 \
      __syncthreads();                                   /* LDS visible for t+1 */   \
    }                                                                                \
  }

__global__ __launch_bounds__(512, 2) void rnn_fused(
    const unsigned short* __restrict__ whh0,
    const unsigned short* __restrict__ wih1,
    const unsigned short* __restrict__ whh1,
    const unsigned short* __restrict__ xp,     // xp0 = x@Wih0^T + b  [B][T][H]
    const float* __restrict__ bias1,           // bih1 + bhh1
    unsigned short* __restrict__ h1buf,        // H1 [B][T][H] (full, no overwrite)
    unsigned short* __restrict__ h2pp,         // [2][B][H]; final h2 in slot 1
    int* __restrict__ bar)
{
  // 35,328 B static LDS (stay < 64KB — r10 lesson)
  __shared__ unsigned short lds_h1[8][1040];   // L0 uses rows 0..3 only
  __shared__ unsigned short lds_h2[8][1040];
  __shared__ float comb[4][8][16];             // L1 aH handoff

  const int wg = blockIdx.x;            // 0..255
  const int tid = threadIdx.x;          // 0..511
  const int l = tid & 63;
  const int w = tid >> 6;               // 0..7
  const int lrow = l & 15;
  const int lk8 = (l >> 4) * 8;

  if (wg < 128) {
    // ================= LAYER 0 (r5 verbatim, publish-all-t) =================
    const int sg = wg & 15;             // 4 samples
    const int rgO = wg >> 4;            // 0..7 (128 cols)
    const int col = rgO*128 + w*16 + lrow;
    const int arow = lrow & 3;
    int* flags0g = bar + sg*16;

    short8 breg[32];
    #pragma unroll
    for (int kk=0; kk<32; ++kk)
      breg[kk] = pinned_load16(&whh0[(size_t)col*H_ + kk*32 + lk8]);

    unsigned int xa[4], xb[4];
    #pragma unroll
    for (int r=0; r<4; ++r) {
      asm volatile("global_load_ushort %0, %1, off" : "=v"(xa[r])
        : "v"(xp + ((size_t)(sg*4+r)*T_ + 0)*H_ + col) : "memory");
      asm volatile("global_load_ushort %0, %1, off" : "=v"(xb[r])
        : "v"(xp + ((size_t)(sg*4+r)*T_ + 1)*H_ + col) : "memory");
    }
    asm volatile("s_waitcnt vmcnt(0)" ::: "memory");
    __builtin_amdgcn_sched_barrier(0);

    for (int t2 = 0; t2 < T_; t2 += 2) {
      L0_STEP(t2,   xa);
      L0_STEP(t2+1, xb);
    }
  } else {
    // ================= LAYER 1 (wave-role split, self-paced) =================
    const int lw = wg - 128;
    const int sg1 = lw >> 4;            // 0..7 (8 samples)
    const int rgO1 = lw & 15;           // 0..15 (64 cols)
    const int q = w & 3;                // col quad within wg
    const bool isI = (w < 4);           // waves 0-3: Wih1; 4-7: Whh1
    const int col = rgO1*64 + q*16 + lrow;
    const int arow = lrow & 7;          // 8 samples dup to 16 rows
    int* flags1g = bar + 1024 + sg1*16;
    const int fi0 = (2*sg1 + ((l>>3)&1))*16 + (l&7);   // L0 flags for my samples

    const unsigned short* wsel = isI ? wih1 : whh1;
    short8 breg[32];
    #pragma unroll
    for (int kk=0; kk<32; ++kk)
      breg[kk] = pinned_load16(&wsel[(size_t)col*H_ + kk*32 + lk8]);
    asm volatile("s_waitcnt vmcnt(0)" ::: "memory");
    __builtin_amdgcn_sched_barrier(0);

    const float b1v = bias1[col];

    // prologue: wait h1_0, stage into lds_h1 (wave w -> sample row w)
    { int fv;
      do { fv = __hip_atomic_load(bar + fi0, __ATOMIC_RELAXED,
                                  __HIP_MEMORY_SCOPE_AGENT);
      } while (!__all(fv >= 1)); }
    {
      short8 s0 = load16_sc(h1buf + ((size_t)(sg1*8 + w)*T_ + 0)*H_ + l*8);
      short8 s1 = load16_sc(h1buf + ((size_t)(sg1*8 + w)*T_ + 0)*H_ + 512 + l*8);
      asm volatile("s_waitcnt vmcnt(0)" ::: "memory");
      *(short8*)&lds_h1[w][l*8]       = s0;
      *(short8*)&lds_h1[w][512 + l*8] = s1;
      __syncthreads();
    }

    for (int s = 0; s < T_; ++s) {
      f32x4 a0 = {}, a1 = {};
      if (isI) {
        #pragma unroll
        for (int kk = 0; kk < 32; kk += 2) {
          short8 x0 = *(const short8*)&lds_h1[arow][(kk+0)*32 + lk8];
          short8 x1 = *(const short8*)&lds_h1[arow][(kk+1)*32 + lk8];
          a0 = __builtin_amdgcn_mfma_f32_16x16x32_bf16(x0, breg[kk+0], a0, 0,0,0);
          a1 = __builtin_amdgcn_mfma_f32_16x16x32_bf16(x1, breg[kk+1], a1, 0,0,0);
        }
      } else {
        if (s > 0) {
          #pragma unroll
          for (int kk = 0; kk < 32; kk += 2) {
            short8 x0 = *(const short8*)&lds_h2[arow][(kk+0)*32 + lk8];
            short8 x1 = *(const short8*)&lds_h2[arow][(kk+1)*32 + lk8];
            a0 = __builtin_amdgcn_mfma_f32_16x16x32_bf16(x0, breg[kk+0], a0, 0,0,0);
            a1 = __builtin_amdgcn_mfma_f32_16x16x32_bf16(x1, breg[kk+1], a1, 0,0,0);
          }
        }
        if (l < 32) {
          #pragma unroll
          for (int r = 0; r < 4; ++r)
            comb[q][(l>>4)*4 + r][lrow] = a0[r] + a1[r];
        }
      }
      __syncthreads();                                   // comb visible
      if (isI && l < 32) {
        #pragma unroll
        for (int r = 0; r < 4; ++r) {
          const int smp = sg1*8 + (l>>4)*4 + r;
          float v = a0[r] + a1[r] + comb[q][(l>>4)*4 + r][lrow] + b1v;
          v = fmaxf(v, 0.f);
          store_short_sc(h2pp + ((size_t)((s&1)*B_ + smp))*H_ + col, f32_to_bf16(v));
        }
      }
      if (s < T_-1) {
        // ---- r17: r15 order, h1-read RT folded under poll1 ----
        // (1) flags0 poll — first read's result-wait drains own h2 stores
        { int v0;
          do { v0 = __hip_atomic_load(bar + fi0, __ATOMIC_RELAXED,
                                      __HIP_MEMORY_SCOPE_AGENT);
          } while (!__all(v0 >= s+2)); }
        // (2) issue h1_{s+1} loads — stay outstanding across sync+publish
        short8 t0 = load16_sc(h1buf + ((size_t)(sg1*8 + w)*T_ + (s+1))*H_ + l*8);
        short8 t1 = load16_sc(h1buf + ((size_t)(sg1*8 + w)*T_ + (s+1))*H_ + 512 + l*8);
        // (3) sync (every wave past poll0 => its h2 stores drained) + publish
        __syncthreads();
        if (tid == 0) store_int_sc(&flags1g[rgO1], s+1);
        // (4) flags1 poll — its load-result wait drains the h1 loads (overlap)
        { int v1;
          do { v1 = __hip_atomic_load(flags1g + (l & 15), __ATOMIC_RELAXED,
                                      __HIP_MEMORY_SCOPE_AGENT);
          } while (!__all(v1 >= s+1)); }
        // (5) h2 loads + drain + LDS + sync
        short8 t2 = load16_sc(h2pp + ((size_t)((s&1)*B_ + sg1*8 + w))*H_ + l*8);
        short8 t3 = load16_sc(h2pp + ((size_t)((s&1)*B_ + sg1*8 + w))*H_ + 512 + l*8);
        asm volatile("s_waitcnt vmcnt(0)" ::: "memory");
        *(short8*)&lds_h1[w][l*8]       = t0;
        *(short8*)&lds_h1[w][512 + l*8] = t1;
        *(short8*)&lds_h2[w][l*8]       = t2;
        *(short8*)&lds_h2[w][512 + l*8] = t3;
        __syncthreads();
      } else {
        // final step: drain h2_511 stores before kernel end (fc reads next)
        asm volatile("s_waitcnt vmcnt(0)" ::: "memory");
      }
    }
  }
}

// ---------- final FC: out[64,256] = h2 @ fcW^T + fcb (f32 out) ----------
__global__ __launch_bounds__(64) void fc_kernel(const unsigned short* __restrict__ h,
                                                const unsigned short* __restrict__ fw,
                                                const float* __restrict__ fb,
                                                float* __restrict__ out) {
  const int l = threadIdx.x;
  const int bx = blockIdx.x, by = blockIdx.y;   // bx: 16 col tiles, by: 4 row tiles
  const int lrow = l & 15, lk8 = (l>>4)*8;
  f32x4 acc = {};
  #pragma unroll
  for (int kk=0; kk<32; ++kk) {
    short8 a = *(const short8*)&h [(size_t)(by*16 + lrow)*H_ + kk*32 + lk8];
    short8 b = *(const short8*)&fw[(size_t)(bx*16 + lrow)*H_ + kk*32 + lk8];
    acc = __builtin_amdgcn_mfma_f32_16x16x32_bf16(a, b, acc, 0,0,0);
  }
  const int col = bx*16 + lrow;
  const float bv = fb[col];
  #pragma unroll
  for (int r=0;r<4;++r) {
    const int row = by*16 + (l>>4)*4 + r;
    out[row*O_ + col] = acc[r] + bv;
  }
}

// ---------- launch ----------
extern "C" void kernel_launch(void* const* d_in, const int* in_sizes, int n_in,
                              void* d_out, int out_size, void* d_ws, size_t ws_size,
                              hipStream_t stream) {
  const float* x    = (const float*)d_in[0];
  const float* wih0 = (const float*)d_in[1];
  const float* bih0 = (const float*)d_in[2];
  const float* whh0 = (const float*)d_in[3];
  const float* bhh0 = (const float*)d_in[4];
  const float* wih1 = (const float*)d_in[5];
  const float* bih1 = (const float*)d_in[6];
  const float* whh1 = (const float*)d_in[7];
  const float* bhh1 = (const float*)d_in[8];
  const float* fcw  = (const float*)d_in[9];
  const float* fcb  = (const float*)d_in[10];

  char* ws = (char*)d_ws;
  // workspace layout (bytes)
  unsigned short* XBF  = (unsigned short*)(ws + 0);          // 16,777,216  x bf16
  unsigned short* WIH0 = (unsigned short*)(ws + 16777216);   //    524,288
  unsigned short* WHH0 = (unsigned short*)(ws + 17301504);   //  2,097,152
  unsigned short* WIH1 = (unsigned short*)(ws + 19398656);   //  2,097,152
  unsigned short* WHH1 = (unsigned short*)(ws + 21495808);   //  2,097,152
  unsigned short* FCW  = (unsigned short*)(ws + 23592960);   //    524,288
  float*          BIAS0= (float*)(ws + 24117248);            //      4,096
  float*          BIAS1= (float*)(ws + 24121344);            //      4,096
  unsigned short* XP   = (unsigned short*)(ws + 24125440);   // 67,108,864  xp0 [B][T][H]
  unsigned short* H1   = (unsigned short*)(ws + 91234304);   // 67,108,864  h1 [B][T][H]
  unsigned short* H2PP = (unsigned short*)(ws + 158343168);  //    262,144  h2 ping-pong
  int*            BAR  = (int*)(ws + 158605312);             //      8,192  flag lines

  // flags0 at BAR[0..255], flags1 at BAR[1024..1151] — all re-zeroed in-graph
  hipMemsetAsync(BAR, 0, 8192, stream);

  // fp32 -> bf16 conversions
  cvt_f32_bf16<<<dim3(8192), 256, 0, stream>>>((const float4*)x,    (ushort4*)XBF,  2097152);
  cvt_f32_bf16<<<dim3(256),  256, 0, stream>>>((const float4*)wih0, (ushort4*)WIH0, 65536);
  cvt_f32_bf16<<<dim3(1024), 256, 0, stream>>>((const float4*)whh0, (ushort4*)WHH0, 262144);
  cvt_f32_bf16<<<dim3(1024), 256, 0, stream>>>((const float4*)wih1, (ushort4*)WIH1, 262144);
  cvt_f32_bf16<<<dim3(1024), 256, 0, stream>>>((const float4*)whh1, (ushort4*)WHH1, 262144);
  cvt_f32_bf16<<<dim3(256),  256, 0, stream>>>((const float4*)fcw,  (ushort4*)FCW,  65536);
  bias_sum<<<dim3(4), 256, 0, stream>>>(bih0, bhh0, BIAS0, H_);
  bias_sum<<<dim3(4), 256, 0, stream>>>(bih1, bhh1, BIAS1, H_);

  // xp0 = x @ Wih0^T + (bih0+bhh0)   [M=32768, N=1024, K=256]
  gemm_bt<0><<<dim3(8, 256), 256, 0, stream>>>(XBF, WIH0, BIAS0, XP, H_, I_);
  // fused decoupled 2-layer scan; final h2 lands in H2PP slot 1
  rnn_fused<<<dim3(256), 512, 0, stream>>>(WHH0, WIH1, WHH1, XP, BIAS1, H1, H2PP, BAR);
  // out = h2_last @ fcW^T + fcb
  fc_kernel<<<dim3(16, 4), 64, 0, stream>>>(H2PP + (size_t)B_*H_, FCW, fcb, (float*)d_out);
}

// Round 18
// 1908.241 us; speedup vs baseline: 1.0931x; 1.0524x over previous
//
#include <hip/hip_runtime.h>
#include <cstdint>
#include <cstddef>

// ---------- types ----------
typedef __attribute__((ext_vector_type(8))) short short8;   // 8 bf16 in 4 VGPRs
typedef __attribute__((ext_vector_type(4))) float f32x4;

#define B_ 64
#define T_ 512
#define I_ 256
#define H_ 1024
#define O_ 256

__device__ __forceinline__ unsigned short f32_to_bf16(float f) {
  unsigned int u = __float_as_uint(f);
  u += 0x7fffu + ((u >> 16) & 1u);           // RNE
  return (unsigned short)(u >> 16);
}
__device__ __forceinline__ float bf16_to_f32(unsigned short h) {
  return __uint_as_float(((unsigned int)h) << 16);
}

__device__ __forceinline__ void gload_lds16(const void* g, void* l) {
  __builtin_amdgcn_global_load_lds((const __attribute__((address_space(1))) void*)g,
                                   (__attribute__((address_space(3))) void*)l, 16, 0, 0);
}

// MALL-write-through stores (bypass L1/L2 -> no cache maintenance ever needed)
__device__ __forceinline__ void store_short_sc(void* p, unsigned short v) {
  unsigned int vv = v;
  asm volatile("global_store_short %0, %1, off sc0 sc1" :: "v"(p), "v"(vv) : "memory");
}
__device__ __forceinline__ void store_int_sc(void* p, int v) {
  asm volatile("global_store_dword %0, %1, off sc0 sc1" :: "v"(p), "v"(v) : "memory");
}
// MALL-coherent 16B load (inline asm: caller MUST s_waitcnt vmcnt before use!)
__device__ __forceinline__ short8 load16_sc(const void* p) {
  short8 r;
  asm volatile("global_load_dwordx4 %0, %1, off sc0 sc1" : "=v"(r) : "v"(p) : "memory");
  return r;
}
// pinned (non-rematerializable) 16B load: executes exactly once (cached path ok)
__device__ __forceinline__ short8 pinned_load16(const void* p) {
  short8 r;
  asm volatile("global_load_dwordx4 %0, %1, off" : "=v"(r) : "v"(p));
  return r;
}

// ---------- conversion kernels ----------
__global__ void cvt_f32_bf16(const float4* __restrict__ s, ushort4* __restrict__ d, int n4) {
  int i = blockIdx.x * blockDim.x + threadIdx.x;
  if (i >= n4) return;
  float4 v = s[i];
  ushort4 o;
  o.x = f32_to_bf16(v.x); o.y = f32_to_bf16(v.y);
  o.z = f32_to_bf16(v.z); o.w = f32_to_bf16(v.w);
  d[i] = o;
}

__global__ void bias_sum(const float* __restrict__ a, const float* __restrict__ b,
                         float* __restrict__ o, int n) {
  int i = blockIdx.x * blockDim.x + threadIdx.x;
  if (i < n) o[i] = a[i] + b[i];
}

// ---------- GEMM: C[M,N] = A[M,K] @ Bm[N,K]^T + bias, 128x128 tile (m97 structure) ----------
template<int OUT_F32>
__global__ __launch_bounds__(256) void gemm_bt(
    const unsigned short* __restrict__ A, const unsigned short* __restrict__ Bm,
    const float* __restrict__ bias, void* __restrict__ Cout, int N_, int K_)
{
  __shared__ unsigned short As[128*32];
  __shared__ unsigned short Bs[128*32];
  const int tid = threadIdx.x;
  const int l = tid & 63, w = tid >> 6;
  const int row0 = blockIdx.y * 128, col0 = blockIdx.x * 128;
  const int wr = w >> 1, wc = w & 1;          // 2x2 waves, each 64x64
  const int lrow = l & 15, lk8 = (l >> 4) * 8;

  f32x4 acc[4][4] = {};

  const int nkb = K_ >> 5;
  for (int kb = 0; kb < nkb; ++kb) {
    #pragma unroll
    for (int c = 0; c < 2; ++c) {
      const int off = w*2048 + c*1024 + l*16;   // byte offset within 8KB tile
      const int row = off >> 6, colb = off & 63;
      gload_lds16((const char*)A  + ((size_t)(row0+row)*K_ + kb*32)*2 + colb,
                  (char*)As + w*2048 + c*1024);
      gload_lds16((const char*)Bm + ((size_t)(col0+row)*K_ + kb*32)*2 + colb,
                  (char*)Bs + w*2048 + c*1024);
    }
    __syncthreads();
    short8 af[4], bfr[4];
    #pragma unroll
    for (int m=0;m<4;++m) af[m]  = *(const short8*)&As[(wr*64 + m*16 + lrow)*32 + lk8];
    #pragma unroll
    for (int n=0;n<4;++n) bfr[n] = *(const short8*)&Bs[(wc*64 + n*16 + lrow)*32 + lk8];
    #pragma unroll
    for (int m=0;m<4;++m)
      #pragma unroll
      for (int n=0;n<4;++n)
        acc[m][n] = __builtin_amdgcn_mfma_f32_16x16x32_bf16(af[m], bfr[n], acc[m][n], 0,0,0);
    __syncthreads();
  }

  #pragma unroll
  for (int n=0;n<4;++n) {
    const int col = col0 + wc*64 + n*16 + lrow;
    const float bv = bias[col];
    #pragma unroll
    for (int m=0;m<4;++m) {
      const int rowb = row0 + wr*64 + m*16 + (l>>4)*4;
      #pragma unroll
      for (int r=0;r<4;++r) {
        const float v = acc[m][n][r] + bv;
        if (OUT_F32) ((float*)Cout)[(size_t)(rowb+r)*N_ + col] = v;
        else ((unsigned short*)Cout)[(size_t)(rowb+r)*N_ + col] = f32_to_bf16(v);
      }
    }
  }
}

// ---------- fused decoupled 2-layer RNN (TERMINAL = r15, best measured) ----------
// 256 wgs x 512 threads, LB(512,2) — 1 wg/CU on all 256 CUs.
// ENVELOPE LAW (r6/7/8/10/14): 512-thr wg => 2 waves/SIMD => <=256 regs/wave
// TOTAL; never asm-pin more than 128 regs/wave.
// wgs 0-127: LAYER 0 = r5's proven scan (fan-in 8, ~2.4us/step), publish-all-t.
// wgs 128-255: LAYER 1 wave-role split (waves 0-3 pin Wih1 -> aI; waves 4-7
//   pin Whh1 -> aH; LDS comb handoff). Fan-in 16 (structurally forced).
// L1 staging (r15): poll0 rides the h2-store drain; h1 loads issued before the
// shared drain; publish; poll1; h2 loads. Later reorderings (r16 publish-first,
// r17 RT-folding) both regressed — this ordering is the measured floor.
// FLOOR: 512 sequential steps x ~3 MALL RTs/step; ~1.9ms. Latency-bound
// (HBM 5%, MfmaUtil 11%) — no cheaper cross-CU sync exists on CDNA4.
#define L0_STEP(tcur, XREG)                                                          \
  {                                                                                  \
    const int t = (tcur);                                                            \
    f32x4 acc0 = {}, acc1 = {}, acc2 = {}, acc3 = {};                                \
    if (t > 0) {                                                                     \
      _Pragma("unroll")                                                              \
      for (int kk = 0; kk < 32; kk += 4) {                                           \
        short8 a0 = *(const short8*)&lds_h1[arow][(kk+0)*32 + lk8];                  \
        short8 a1 = *(const short8*)&lds_h1[arow][(kk+1)*32 + lk8];                  \
        short8 a2 = *(const short8*)&lds_h1[arow][(kk+2)*32 + lk8];                  \
        short8 a3 = *(const short8*)&lds_h1[arow][(kk+3)*32 + lk8];                  \
        acc0 = __builtin_amdgcn_mfma_f32_16x16x32_bf16(a0, breg[kk+0], acc0, 0,0,0); \
        acc1 = __builtin_amdgcn_mfma_f32_16x16x32_bf16(a1, breg[kk+1], acc1, 0,0,0); \
        acc2 = __builtin_amdgcn_mfma_f32_16x16x32_bf16(a2, breg[kk+2], acc2, 0,0,0); \
        acc3 = __builtin_amdgcn_mfma_f32_16x16x32_bf16(a3, breg[kk+3], acc3, 0,0,0); \
      }                                                                              \
    }                                                                                \
    if (l < 16) {                                                                    \
      _Pragma("unroll")                                                              \
      for (int r = 0; r < 4; ++r) {                                                  \
        const int s = sg*4 + r;                                                      \
        float v = acc0[r] + acc1[r] + acc2[r] + acc3[r]                              \
                + bf16_to_f32((unsigned short)XREG[r]);                              \
        v = fmaxf(v, 0.f);                                                           \
        store_short_sc(h1buf + ((size_t)s*T_ + t)*H_ + col, f32_to_bf16(v));         \
      }                                                                              \
    }                                                                                \
    asm volatile("s_waitcnt vmcnt(0)" ::: "memory");     /* h1 stores at MALL */     \
    __syncthreads();                                     /* all 8 waves drained */   \
    if (tid == 0) store_int_sc(&flags0g[rgO], t+1);      /* publish ALL t */         \
    if (t < T_-1) {                                                                  \
      { int fv;                                                                      \
        do { fv = __hip_atomic_load(flags0g + (l & 7), __ATOMIC_RELAXED,             \
                                    __HIP_MEMORY_SCOPE_AGENT);                       \
        } while (!__all(fv >= t+1)); }                                               \
      const unsigned short* hrow = h1buf + ((size_t)(sg*4 + (w>>1))*T_ + t)*H_;      \
      const int tn = (t+2 < T_) ? (t+2) : (T_-1);                                    \
      const unsigned short* xpp = xp + ((size_t)(sg*4)*T_ + tn)*H_ + col;            \
      short8 sv = load16_sc(hrow + (w&1)*512 + l*8);     /* 1 outstanding */         \
      _Pragma("unroll")                                                              \
      for (int r = 0; r < 4; ++r)                        /* +4 outstanding */        \
        asm volatile("global_load_ushort %0, %1, off"                               \
                     : "=v"(XREG[r]) : "v"(xpp + (size_t)r*T_*H_) : "memory");       \
      asm volatile("s_waitcnt vmcnt(4)" ::: "memory");   /* wait stage load only */  \
      *(short8*)&lds_h1[w>>1][(w&1)*512 + l*8] = sv;                                 \
      __syncthreads();                                   /* LDS visible for t+1 */   \
    }                                                                                \
  }

__global__ __launch_bounds__(512, 2) void rnn_fused(
    const unsigned short* __restrict__ whh0,
    const unsigned short* __restrict__ wih1,
    const unsigned short* __restrict__ whh1,
    const unsigned short* __restrict__ xp,     // xp0 = x@Wih0^T + b  [B][T][H]
    const float* __restrict__ bias1,           // bih1 + bhh1
    unsigned short* __restrict__ h1buf,        // H1 [B][T][H] (full, no overwrite)
    unsigned short* __restrict__ h2pp,         // [2][B][H]; final h2 in slot 1
    int* __restrict__ bar)
{
  // 35,328 B static LDS (stay < 64KB — r10 lesson)
  __shared__ unsigned short lds_h1[8][1040];   // L0 uses rows 0..3 only
  __shared__ unsigned short lds_h2[8][1040];
  __shared__ float comb[4][8][16];             // L1 aH handoff

  const int wg = blockIdx.x;            // 0..255
  const int tid = threadIdx.x;          // 0..511
  const int l = tid & 63;
  const int w = tid >> 6;               // 0..7
  const int lrow = l & 15;
  const int lk8 = (l >> 4) * 8;

  if (wg < 128) {
    // ================= LAYER 0 (r5 verbatim, publish-all-t) =================
    const int sg = wg & 15;             // 4 samples
    const int rgO = wg >> 4;            // 0..7 (128 cols)
    const int col = rgO*128 + w*16 + lrow;
    const int arow = lrow & 3;
    int* flags0g = bar + sg*16;

    short8 breg[32];
    #pragma unroll
    for (int kk=0; kk<32; ++kk)
      breg[kk] = pinned_load16(&whh0[(size_t)col*H_ + kk*32 + lk8]);

    unsigned int xa[4], xb[4];
    #pragma unroll
    for (int r=0; r<4; ++r) {
      asm volatile("global_load_ushort %0, %1, off" : "=v"(xa[r])
        : "v"(xp + ((size_t)(sg*4+r)*T_ + 0)*H_ + col) : "memory");
      asm volatile("global_load_ushort %0, %1, off" : "=v"(xb[r])
        : "v"(xp + ((size_t)(sg*4+r)*T_ + 1)*H_ + col) : "memory");
    }
    asm volatile("s_waitcnt vmcnt(0)" ::: "memory");
    __builtin_amdgcn_sched_barrier(0);

    for (int t2 = 0; t2 < T_; t2 += 2) {
      L0_STEP(t2,   xa);
      L0_STEP(t2+1, xb);
    }
  } else {
    // ================= LAYER 1 (wave-role split, self-paced) =================
    const int lw = wg - 128;
    const int sg1 = lw >> 4;            // 0..7 (8 samples)
    const int rgO1 = lw & 15;           // 0..15 (64 cols)
    const int q = w & 3;                // col quad within wg
    const bool isI = (w < 4);           // waves 0-3: Wih1; 4-7: Whh1
    const int col = rgO1*64 + q*16 + lrow;
    const int arow = lrow & 7;          // 8 samples dup to 16 rows
    int* flags1g = bar + 1024 + sg1*16;
    const int fi0 = (2*sg1 + ((l>>3)&1))*16 + (l&7);   // L0 flags for my samples

    const unsigned short* wsel = isI ? wih1 : whh1;
    short8 breg[32];
    #pragma unroll
    for (int kk=0; kk<32; ++kk)
      breg[kk] = pinned_load16(&wsel[(size_t)col*H_ + kk*32 + lk8]);
    asm volatile("s_waitcnt vmcnt(0)" ::: "memory");
    __builtin_amdgcn_sched_barrier(0);

    const float b1v = bias1[col];

    // prologue: wait h1_0, stage into lds_h1 (wave w -> sample row w)
    { int fv;
      do { fv = __hip_atomic_load(bar + fi0, __ATOMIC_RELAXED,
                                  __HIP_MEMORY_SCOPE_AGENT);
      } while (!__all(fv >= 1)); }
    {
      short8 s0 = load16_sc(h1buf + ((size_t)(sg1*8 + w)*T_ + 0)*H_ + l*8);
      short8 s1 = load16_sc(h1buf + ((size_t)(sg1*8 + w)*T_ + 0)*H_ + 512 + l*8);
      asm volatile("s_waitcnt vmcnt(0)" ::: "memory");
      *(short8*)&lds_h1[w][l*8]       = s0;
      *(short8*)&lds_h1[w][512 + l*8] = s1;
      __syncthreads();
    }

    for (int s = 0; s < T_; ++s) {
      f32x4 a0 = {}, a1 = {};
      if (isI) {
        #pragma unroll
        for (int kk = 0; kk < 32; kk += 2) {
          short8 x0 = *(const short8*)&lds_h1[arow][(kk+0)*32 + lk8];
          short8 x1 = *(const short8*)&lds_h1[arow][(kk+1)*32 + lk8];
          a0 = __builtin_amdgcn_mfma_f32_16x16x32_bf16(x0, breg[kk+0], a0, 0,0,0);
          a1 = __builtin_amdgcn_mfma_f32_16x16x32_bf16(x1, breg[kk+1], a1, 0,0,0);
        }
      } else {
        if (s > 0) {
          #pragma unroll
          for (int kk = 0; kk < 32; kk += 2) {
            short8 x0 = *(const short8*)&lds_h2[arow][(kk+0)*32 + lk8];
            short8 x1 = *(const short8*)&lds_h2[arow][(kk+1)*32 + lk8];
            a0 = __builtin_amdgcn_mfma_f32_16x16x32_bf16(x0, breg[kk+0], a0, 0,0,0);
            a1 = __builtin_amdgcn_mfma_f32_16x16x32_bf16(x1, breg[kk+1], a1, 0,0,0);
          }
        }
        if (l < 32) {
          #pragma unroll
          for (int r = 0; r < 4; ++r)
            comb[q][(l>>4)*4 + r][lrow] = a0[r] + a1[r];
        }
      }
      __syncthreads();                                   // comb visible
      if (isI && l < 32) {
        #pragma unroll
        for (int r = 0; r < 4; ++r) {
          const int smp = sg1*8 + (l>>4)*4 + r;
          float v = a0[r] + a1[r] + comb[q][(l>>4)*4 + r][lrow] + b1v;
          v = fmaxf(v, 0.f);
          store_short_sc(h2pp + ((size_t)((s&1)*B_ + smp))*H_ + col, f32_to_bf16(v));
        }
      }
      if (s < T_-1) {
        // ---- r15 staging (measured best): poll0 rides the store drain ----
        // (1) flags0 poll (single load) — L0 leads; RT overlaps our h2 stores
        { int v0;
          do { v0 = __hip_atomic_load(bar + fi0, __ATOMIC_RELAXED,
                                      __HIP_MEMORY_SCOPE_AGENT);
          } while (!__all(v0 >= s+2)); }
        // (2) issue h1_{s+1} stage loads — drain together with the h2 stores
        short8 t0 = load16_sc(h1buf + ((size_t)(sg1*8 + w)*T_ + (s+1))*H_ + l*8);
        short8 t1 = load16_sc(h1buf + ((size_t)(sg1*8 + w)*T_ + (s+1))*H_ + 512 + l*8);
        // (3) shared drain: h2 stores AND h1 loads at/back-from MALL
        asm volatile("s_waitcnt vmcnt(0)" ::: "memory");
        __syncthreads();                                  // all 8 waves drained
        if (tid == 0) store_int_sc(&flags1g[rgO1], s+1);
        // (4) flags1 poll (single load per iteration)
        { int v1;
          do { v1 = __hip_atomic_load(flags1g + (l & 15), __ATOMIC_RELAXED,
                                      __HIP_MEMORY_SCOPE_AGENT);
          } while (!__all(v1 >= s+1)); }
        // (5) h2 loads + drain + LDS + sync
        short8 t2 = load16_sc(h2pp + ((size_t)((s&1)*B_ + sg1*8 + w))*H_ + l*8);
        short8 t3 = load16_sc(h2pp + ((size_t)((s&1)*B_ + sg1*8 + w))*H_ + 512 + l*8);
        asm volatile("s_waitcnt vmcnt(0)" ::: "memory");
        *(short8*)&lds_h1[w][l*8]       = t0;
        *(short8*)&lds_h1[w][512 + l*8] = t1;
        *(short8*)&lds_h2[w][l*8]       = t2;
        *(short8*)&lds_h2[w][512 + l*8] = t3;
        __syncthreads();
      } else {
        // final step: drain h2_511 stores before kernel end (fc reads next)
        asm volatile("s_waitcnt vmcnt(0)" ::: "memory");
      }
    }
  }
}

// ---------- final FC: out[64,256] = h2 @ fcW^T + fcb (f32 out) ----------
__global__ __launch_bounds__(64) void fc_kernel(const unsigned short* __restrict__ h,
                                                const unsigned short* __restrict__ fw,
                                                const float* __restrict__ fb,
                                                float* __restrict__ out) {
  const int l = threadIdx.x;
  const int bx = blockIdx.x, by = blockIdx.y;   // bx: 16 col tiles, by: 4 row tiles
  const int lrow = l & 15, lk8 = (l>>4)*8;
  f32x4 acc = {};
  #pragma unroll
  for (int kk=0; kk<32; ++kk) {
    short8 a = *(const short8*)&h [(size_t)(by*16 + lrow)*H_ + kk*32 + lk8];
    short8 b = *(const short8*)&fw[(size_t)(bx*16 + lrow)*H_ + kk*32 + lk8];
    acc = __builtin_amdgcn_mfma_f32_16x16x32_bf16(a, b, acc, 0,0,0);
  }
  const int col = bx*16 + lrow;
  const float bv = fb[col];
  #pragma unroll
  for (int r=0;r<4;++r) {
    const int row = by*16 + (l>>4)*4 + r;
    out[row*O_ + col] = acc[r] + bv;
  }
}

// ---------- launch ----------
extern "C" void kernel_launch(void* const* d_in, const int* in_sizes, int n_in,
                              void* d_out, int out_size, void* d_ws, size_t ws_size,
                              hipStream_t stream) {
  const float* x    = (const float*)d_in[0];
  const float* wih0 = (const float*)d_in[1];
  const float* bih0 = (const float*)d_in[2];
  const float* whh0 = (const float*)d_in[3];
  const float* bhh0 = (const float*)d_in[4];
  const float* wih1 = (const float*)d_in[5];
  const float* bih1 = (const float*)d_in[6];
  const float* whh1 = (const float*)d_in[7];
  const float* bhh1 = (const float*)d_in[8];
  const float* fcw  = (const float*)d_in[9];
  const float* fcb  = (const float*)d_in[10];

  char* ws = (char*)d_ws;
  // workspace layout (bytes)
  unsigned short* XBF  = (unsigned short*)(ws + 0);          // 16,777,216  x bf16
  unsigned short* WIH0 = (unsigned short*)(ws + 16777216);   //    524,288
  unsigned short* WHH0 = (unsigned short*)(ws + 17301504);   //  2,097,152
  unsigned short* WIH1 = (unsigned short*)(ws + 19398656);   //  2,097,152
  unsigned short* WHH1 = (unsigned short*)(ws + 21495808);   //  2,097,152
  unsigned short* FCW  = (unsigned short*)(ws + 23592960);   //    524,288
  float*          BIAS0= (float*)(ws + 24117248);            //      4,096
  float*          BIAS1= (float*)(ws + 24121344);            //      4,096
  unsigned short* XP   = (unsigned short*)(ws + 24125440);   // 67,108,864  xp0 [B][T][H]
  unsigned short* H1   = (unsigned short*)(ws + 91234304);   // 67,108,864  h1 [B][T][H]
  unsigned short* H2PP = (unsigned short*)(ws + 158343168);  //    262,144  h2 ping-pong
  int*            BAR  = (int*)(ws + 158605312);             //      8,192  flag lines

  // flags0 at BAR[0..255], flags1 at BAR[1024..1151] — all re-zeroed in-graph
  hipMemsetAsync(BAR, 0, 8192, stream);

  // fp32 -> bf16 conversions
  cvt_f32_bf16<<<dim3(8192), 256, 0, stream>>>((const float4*)x,    (ushort4*)XBF,  2097152);
  cvt_f32_bf16<<<dim3(256),  256, 0, stream>>>((const float4*)wih0, (ushort4*)WIH0, 65536);
  cvt_f32_bf16<<<dim3(1024), 256, 0, stream>>>((const float4*)whh0, (ushort4*)WHH0, 262144);
  cvt_f32_bf16<<<dim3(1024), 256, 0, stream>>>((const float4*)wih1, (ushort4*)WIH1, 262144);
  cvt_f32_bf16<<<dim3(1024), 256, 0, stream>>>((const float4*)whh1, (ushort4*)WHH1, 262144);
  cvt_f32_bf16<<<dim3(256),  256, 0, stream>>>((const float4*)fcw,  (ushort4*)FCW,  65536);
  bias_sum<<<dim3(4), 256, 0, stream>>>(bih0, bhh0, BIAS0, H_);
  bias_sum<<<dim3(4), 256, 0, stream>>>(bih1, bhh1, BIAS1, H_);

  // xp0 = x @ Wih0^T + (bih0+bhh0)   [M=32768, N=1024, K=256]
  gemm_bt<0><<<dim3(8, 256), 256, 0, stream>>>(XBF, WIH0, BIAS0, XP, H_, I_);
  // fused decoupled 2-layer scan; final h2 lands in H2PP slot 1
  rnn_fused<<<dim3(256), 512, 0, stream>>>(WHH0, WIH1, WHH1, XP, BIAS1, H1, H2PP, BAR);
  // out = h2_last @ fcW^T + fcb
  fc_kernel<<<dim3(16, 4), 64, 0, stream>>>(H2PP + (size_t)B_*H_, FCW, fcb, (float*)d_out);
}